// Round 1
// baseline (1084.746 us; speedup 1.0000x reference)
//
#include <hip/hip_runtime.h>
#include <math.h>

#define BB 8
#define HH 256
#define WW 256
#define HW (HH*WW)
#define NTOT (BB*HW)

// acc layout (floats):
// 0 ce_sum, 1 inter, 2 sum_probs, 3 sum_t, 4 focal_ce_sum,
// 5..12 counts[b], 13..20 bwsum[b], 21 sum_pb, 22 sum_gb, 23 sum_pbgb
#define ACC_N 24

__device__ __forceinline__ void waveReduceAdd(float* addr, float v, int lane) {
    #pragma unroll
    for (int o = 32; o > 0; o >>= 1) v += __shfl_down(v, o, 64);
    if (lane == 0) atomicAdd(addr, v);
}

__global__ void k_zero(float* acc) {
    if (threadIdx.x < ACC_N) acc[threadIdx.x] = 0.0f;
}

// Pass A: per-pixel CE / probs / focal-BCE partials; store sigmoid(probs).
__global__ void k_main(const float* __restrict__ in, const int* __restrict__ tgt,
                       float* __restrict__ sp_out, float* __restrict__ acc) {
    int idx = blockIdx.x * 256 + threadIdx.x;
    int b   = idx >> 16;           // HW = 65536 per batch
    int hw  = idx & 65535;
    float x0 = in[b * 2 * HW + hw];
    float x1 = in[b * 2 * HW + HW + hw];
    int   tg = tgt[idx];
    float t  = (tg == 1) ? 1.0f : 0.0f;

    float m   = fmaxf(x0, x1);
    float lse = m + log1pf(expf(fminf(x0, x1) - m));
    float ce_e = lse - ((tg == 1) ? x1 : x0);      // -log p_target
    float p   = 1.0f / (1.0f + expf(x0 - x1));     // softmax class-1 prob

    // focal BCE (z in (0,1) used as logits, per original)
    float z   = 1.0f / (1.0f + expf(-10.0f * (p - 0.5f)));
    float tb  = 1.0f / (1.0f + expf(-10.0f * (t - 0.5f)));
    float bce = log1pf(expf(z)) - tb * z;
    float ptb = expf(-bce);
    float omp = 1.0f - ptb;
    float fse = 0.25f * omp * omp * bce;

    sp_out[idx] = 1.0f / (1.0f + expf(-p));        // sigmoid(probs), for boundary dice

    int lane = threadIdx.x & 63;
    waveReduceAdd(&acc[0], ce_e, lane);
    waveReduceAdd(&acc[1], p * t, lane);
    waveReduceAdd(&acc[2], p, lane);
    waveReduceAdd(&acc[3], t, lane);
    waveReduceAdd(&acc[4], fse, lane);
    waveReduceAdd(&acc[5 + b], t, lane);           // per-batch fg count (block is single-batch)
}

// EDT column pass: per-column nearest-background distance, squared.
__global__ void k_edt_col(const int* __restrict__ tgt, float* __restrict__ g) {
    int gid = blockIdx.x * 256 + threadIdx.x;      // BB*WW = 2048 threads
    int b = gid >> 8, w = gid & 255;
    const int* tb = tgt + b * HW + w;
    float* gb = g + b * HW + w;
    int d = 1 << 20;
    for (int h = 0; h < HH; h++) {
        d = (tb[h * WW] == 1) ? (d + 1) : 0;
        gb[h * WW] = (float)d;
    }
    d = 1 << 20;
    for (int h = HH - 1; h >= 0; h--) {
        d = (tb[h * WW] == 1) ? (d + 1) : 0;
        float dv = fminf(gb[h * WW], (float)d);
        gb[h * WW] = (dv >= 1.0e4f) ? 1.0e12f : dv * dv;
    }
}

// EDT row pass + boundary-weight sum. One block per row, g-row staged in LDS.
__global__ void k_edt_row(const float* __restrict__ g, float* __restrict__ acc) {
    __shared__ float s_g[WW];
    int row = blockIdx.x;                          // b*HH + h
    int b = row >> 8;
    int w = threadIdx.x;
    s_g[w] = g[row * WW + w];
    __syncthreads();
    float best = 3.0e12f;
    for (int wp = 0; wp < WW; wp++) {
        int dw = w - wp;
        best = fminf(best, (float)(dw * dw) + s_g[wp]);
    }
    float bw = 10.0f * expf(-best * (1.0f / 98.0f));
    waveReduceAdd(&acc[13 + b], bw, threadIdx.x & 63);
}

// Boundary dice: 7x7 zero-padded box sums, direct.
__global__ void k_boundary(const float* __restrict__ sp, const int* __restrict__ tgt,
                           float* __restrict__ acc) {
    int tid = threadIdx.x;
    int tx = tid & 15, ty = tid >> 4;
    int bx = blockIdx.x & 15;
    int by = (blockIdx.x >> 4) & 15;
    int b  = blockIdx.x >> 8;
    int h = by * 16 + ty, w = bx * 16 + tx;
    const float* spb = sp + b * HW;
    const int*   tb  = tgt + b * HW;
    float cp = 0.0f; int cg = 0;
    #pragma unroll
    for (int dy = -3; dy <= 3; dy++) {
        int hh = h + dy;
        if (hh < 0 || hh >= HH) continue;
        #pragma unroll
        for (int dx = -3; dx <= 3; dx++) {
            int ww = w + dx;
            if (ww < 0 || ww >= WW) continue;
            cp += spb[hh * WW + ww];
            cg += (tb[hh * WW + ww] == 1);
        }
    }
    float pb = (cp > 0.0f && cp < 49.0f) ? 1.0f : 0.0f;
    float gb = (cg > 0 && cg < 49) ? 1.0f : 0.0f;
    int lane = tid & 63;
    waveReduceAdd(&acc[21], pb, lane);
    waveReduceAdd(&acc[22], gb, lane);
    waveReduceAdd(&acc[23], pb * gb, lane);
}

__global__ void k_final(const float* __restrict__ acc, float* __restrict__ out) {
    float ce = acc[0] / (float)NTOT;
    float inter = acc[1], sump = acc[2], sumt = acc[3];
    float dice = 1.0f - (2.0f * inter + 1e-6f) / (sump + sumt + 1e-6f);
    float pt = expf(-ce);
    float focal = 0.25f * (1.0f - pt) * (1.0f - pt) * ce;
    float fp = sump - inter, fn = sumt - inter;
    float tversky = 1.0f - inter / (inter + 0.7f * fp + 0.3f * fn);
    float ftv = tversky * tversky;
    float focal_ce = acc[4] / (float)NTOT;
    // class weights: cw = (1/(c+eps)) normalized; sum(cw) ~= 1, compute faithfully
    float s = 0.0f;
    for (int b = 0; b < BB; b++) s += 1.0f / (acc[5 + b] + 1e-6f);
    float cwsum = 0.0f;
    for (int b = 0; b < BB; b++) cwsum += (1.0f / (acc[5 + b] + 1e-6f)) / s;
    float bwsum = 0.0f;
    for (int b = 0; b < BB; b++) if (acc[5 + b] > 0.0f) bwsum += acc[13 + b];
    float wfce = focal_ce * cwsum * bwsum / ((float)BB * (float)BB * (float)HW);
    float bndice = 1.0f - (2.0f * acc[23] + 1e-6f) / (acc[21] + acc[22] + 1e-6f);
    out[0] = 2.0f * dice + focal + ce + ftv + wfce + bndice;
}

extern "C" void kernel_launch(void* const* d_in, const int* in_sizes, int n_in,
                              void* d_out, int out_size, void* d_ws, size_t ws_size,
                              hipStream_t stream) {
    const float* in  = (const float*)d_in[0];
    const int*   tgt = (const int*)d_in[1];
    float* out = (float*)d_out;
    float* sp  = (float*)d_ws;          // NTOT floats: sigmoid(probs)
    float* g   = sp + NTOT;             // NTOT floats: EDT intermediate
    float* acc = g + NTOT;              // ACC_N floats

    k_zero<<<1, 64, 0, stream>>>(acc);
    k_main<<<NTOT / 256, 256, 0, stream>>>(in, tgt, sp, acc);
    k_edt_col<<<(BB * WW) / 256, 256, 0, stream>>>(tgt, g);
    k_edt_row<<<BB * HH, 256, 0, stream>>>(g, acc);
    k_boundary<<<BB * 16 * 16, 256, 0, stream>>>(sp, tgt, acc);
    k_final<<<1, 1, 0, stream>>>(acc, out);
}

// Round 2
// 209.634 us; speedup vs baseline: 5.1745x; 5.1745x over previous
//
#include <hip/hip_runtime.h>
#include <math.h>

#define BB 8
#define HH 256
#define WW 256
#define HW (HH*WW)
#define NTOT (BB*HW)

// acc layout (floats):
// 0 ce_sum, 1 inter, 2 sum_probs, 3 (unused), 4 focal_ce_sum,
// 5..12 counts[b], 13..20 bwsum[b], 21 sum_pb, 22 sum_gb, 23 sum_pbgb
#define ACC_N 24

// Block-wide reduction (blockDim == 256 = 4 waves) + one atomic per value.
template<int N>
__device__ __forceinline__ void blockAtomicAdd(float (&v)[N], float* const (&dst)[N]) {
    __shared__ float s[N][4];
    int lane = threadIdx.x & 63, wid = threadIdx.x >> 6;
    #pragma unroll
    for (int j = 0; j < N; j++) {
        float x = v[j];
        #pragma unroll
        for (int o = 32; o > 0; o >>= 1) x += __shfl_down(x, o, 64);
        if (lane == 0) s[j][wid] = x;
    }
    __syncthreads();
    if (threadIdx.x < N) {
        float x = s[threadIdx.x][0] + s[threadIdx.x][1] + s[threadIdx.x][2] + s[threadIdx.x][3];
        atomicAdd(dst[threadIdx.x], x);
    }
}

__global__ void k_zero(float* acc) {
    if (threadIdx.x < ACC_N) acc[threadIdx.x] = 0.0f;
}

// Pass A: per-pixel CE / probs / focal-BCE partials; store sigmoid(probs).
// 256 blocks x 256 threads, 8 px/thread; each block within one batch.
__global__ void k_main(const float* __restrict__ in, const int* __restrict__ tgt,
                       float* __restrict__ sp_out, float* __restrict__ acc) {
    int b = blockIdx.x >> 5;                 // 32 blocks per batch (2048 px per block)
    int hwbase = (blockIdx.x & 31) * 2048;
    const float* in0 = in + b * 2 * HW;
    const float* in1 = in0 + HW;

    float ce = 0.f, inter = 0.f, sump = 0.f, fse = 0.f, tc = 0.f;
    #pragma unroll
    for (int k = 0; k < 8; k++) {
        int hw  = hwbase + k * 256 + threadIdx.x;
        int idx = b * HW + hw;
        float x0 = in0[hw], x1 = in1[hw];
        int   tg = tgt[idx];
        float t  = (tg == 1) ? 1.0f : 0.0f;

        float m   = fmaxf(x0, x1);
        float lse = m + log1pf(expf(fminf(x0, x1) - m));
        ce += lse - ((tg == 1) ? x1 : x0);
        float p = 1.0f / (1.0f + expf(x0 - x1));
        inter += p * t;
        sump  += p;
        tc    += t;

        float z   = 1.0f / (1.0f + expf(-10.0f * (p - 0.5f)));
        float tb  = 1.0f / (1.0f + expf(-10.0f * (t - 0.5f)));
        float bce = log1pf(expf(z)) - tb * z;
        float ptb = expf(-bce);
        float omp = 1.0f - ptb;
        fse += 0.25f * omp * omp * bce;

        sp_out[idx] = 1.0f / (1.0f + expf(-p));
    }
    float v[5]   = {ce, inter, sump, fse, tc};
    float* dst[5] = {acc + 0, acc + 1, acc + 2, acc + 4, acc + 5 + b};
    blockAtomicAdd<5>(v, dst);
}

// EDT column pass: per-column nearest-background distance, squared.
__global__ void k_edt_col(const int* __restrict__ tgt, float* __restrict__ g) {
    int gid = blockIdx.x * 256 + threadIdx.x;      // BB*WW = 2048 threads
    int b = gid >> 8, w = gid & 255;
    const int* tb = tgt + b * HW + w;
    float* gb = g + b * HW + w;
    int d = 1 << 20;
    for (int h = 0; h < HH; h++) {
        d = (tb[h * WW] == 1) ? (d + 1) : 0;
        gb[h * WW] = (float)d;
    }
    d = 1 << 20;
    for (int h = HH - 1; h >= 0; h--) {
        d = (tb[h * WW] == 1) ? (d + 1) : 0;
        float dv = fminf(gb[h * WW], (float)d);
        gb[h * WW] = (dv >= 1.0e4f) ? 1.0e12f : dv * dv;
    }
}

// EDT row pass + boundary-weight sum. 256 blocks x 8 rows each.
__global__ void k_edt_row(const float* __restrict__ g, float* __restrict__ acc) {
    __shared__ float s_g[WW];
    int row0 = blockIdx.x * 8;                     // global row = b*HH + h
    int b = row0 >> 8;
    int w = threadIdx.x;
    float bwsum = 0.0f;
    for (int r = 0; r < 8; r++) {
        s_g[w] = g[(row0 + r) * WW + w];
        __syncthreads();
        float best = 3.0e12f;
        for (int wp = 0; wp < WW; wp++) {
            int dw = w - wp;
            best = fminf(best, (float)(dw * dw) + s_g[wp]);
        }
        bwsum += 10.0f * expf(-best * (1.0f / 98.0f));
        __syncthreads();
    }
    float v[1]   = {bwsum};
    float* dst[1] = {acc + 13 + b};
    blockAtomicAdd<1>(v, dst);
}

// Boundary dice: 7x7 zero-padded box sums, direct. 256 blocks x 8 px/thread.
__global__ void k_boundary(const float* __restrict__ sp, const int* __restrict__ tgt,
                           float* __restrict__ acc) {
    int b = blockIdx.x >> 5;
    int hwbase = (blockIdx.x & 31) * 2048;
    const float* spb = sp + b * HW;
    const int*   tb  = tgt + b * HW;
    float vpb = 0.f, vgb = 0.f, vpg = 0.f;
    for (int k = 0; k < 8; k++) {
        int hw = hwbase + k * 256 + threadIdx.x;
        int h = hw >> 8, w = hw & 255;
        float cp = 0.0f; int cg = 0;
        #pragma unroll
        for (int dy = -3; dy <= 3; dy++) {
            int hh = h + dy;
            if (hh < 0 || hh >= HH) continue;
            #pragma unroll
            for (int dx = -3; dx <= 3; dx++) {
                int ww = w + dx;
                if (ww < 0 || ww >= WW) continue;
                cp += spb[hh * WW + ww];
                cg += (tb[hh * WW + ww] == 1);
            }
        }
        float pb = (cp > 0.0f && cp < 49.0f) ? 1.0f : 0.0f;
        float gb = (cg > 0 && cg < 49) ? 1.0f : 0.0f;
        vpb += pb; vgb += gb; vpg += pb * gb;
    }
    float v[3]   = {vpb, vgb, vpg};
    float* dst[3] = {acc + 21, acc + 22, acc + 23};
    blockAtomicAdd<3>(v, dst);
}

__global__ void k_final(const float* __restrict__ acc, float* __restrict__ out) {
    float sumt = 0.0f;
    for (int b = 0; b < BB; b++) sumt += acc[5 + b];
    float ce = acc[0] / (float)NTOT;
    float inter = acc[1], sump = acc[2];
    float dice = 1.0f - (2.0f * inter + 1e-6f) / (sump + sumt + 1e-6f);
    float pt = expf(-ce);
    float focal = 0.25f * (1.0f - pt) * (1.0f - pt) * ce;
    float fp = sump - inter, fn = sumt - inter;
    float tversky = 1.0f - inter / (inter + 0.7f * fp + 0.3f * fn);
    float ftv = tversky * tversky;
    float focal_ce = acc[4] / (float)NTOT;
    float s = 0.0f;
    for (int b = 0; b < BB; b++) s += 1.0f / (acc[5 + b] + 1e-6f);
    float cwsum = 0.0f;
    for (int b = 0; b < BB; b++) cwsum += (1.0f / (acc[5 + b] + 1e-6f)) / s;
    float bwsum = 0.0f;
    for (int b = 0; b < BB; b++) if (acc[5 + b] > 0.0f) bwsum += acc[13 + b];
    float wfce = focal_ce * cwsum * bwsum / ((float)BB * (float)BB * (float)HW);
    float bndice = 1.0f - (2.0f * acc[23] + 1e-6f) / (acc[21] + acc[22] + 1e-6f);
    out[0] = 2.0f * dice + focal + ce + ftv + wfce + bndice;
}

extern "C" void kernel_launch(void* const* d_in, const int* in_sizes, int n_in,
                              void* d_out, int out_size, void* d_ws, size_t ws_size,
                              hipStream_t stream) {
    const float* in  = (const float*)d_in[0];
    const int*   tgt = (const int*)d_in[1];
    float* out = (float*)d_out;
    float* sp  = (float*)d_ws;          // NTOT floats: sigmoid(probs)
    float* g   = sp + NTOT;             // NTOT floats: EDT intermediate
    float* acc = g + NTOT;              // ACC_N floats

    k_zero<<<1, 64, 0, stream>>>(acc);
    k_main<<<256, 256, 0, stream>>>(in, tgt, sp, acc);
    k_edt_col<<<(BB * WW) / 256, 256, 0, stream>>>(tgt, g);
    k_edt_row<<<256, 256, 0, stream>>>(g, acc);
    k_boundary<<<256, 256, 0, stream>>>(sp, tgt, acc);
    k_final<<<1, 1, 0, stream>>>(acc, out);
}

// Round 3
// 91.924 us; speedup vs baseline: 11.8005x; 2.2805x over previous
//
#include <hip/hip_runtime.h>
#include <math.h>

#define BB 8
#define HH 256
#define WW 256
#define HW (HH*WW)
#define NTOT (BB*HW)

// acc layout (floats):
// 0 ce_sum, 1 inter, 2 sum_probs, 3 (unused), 4 focal_ce_sum,
// 5..12 counts[b], 13..20 bwsum[b], 21 sum_pb, 22 sum_gb, 23 sum_pbgb
#define ACC_N 24

#define WIN 48   // EDT row-pass window; contributions beyond are < 1e-9

// Block-wide reduction (blockDim == 256 = 4 waves) + one atomic per value.
template<int N>
__device__ __forceinline__ void blockAtomicAdd(float (&v)[N], float* const (&dst)[N]) {
    __shared__ float s[N][4];
    int lane = threadIdx.x & 63, wid = threadIdx.x >> 6;
    #pragma unroll
    for (int j = 0; j < N; j++) {
        float x = v[j];
        #pragma unroll
        for (int o = 32; o > 0; o >>= 1) x += __shfl_down(x, o, 64);
        if (lane == 0) s[j][wid] = x;
    }
    __syncthreads();
    if (threadIdx.x < N) {
        float x = s[threadIdx.x][0] + s[threadIdx.x][1] + s[threadIdx.x][2] + s[threadIdx.x][3];
        atomicAdd(dst[threadIdx.x], x);
    }
}

__global__ void k_zero(float* acc) {
    if (threadIdx.x < ACC_N) acc[threadIdx.x] = 0.0f;
}

// Stage 1 (fused): blocks 0..511 = per-pixel pass; blocks 512..519 = EDT column pass.
__global__ void k_stage1(const float* __restrict__ in, const int* __restrict__ tgt,
                         float* __restrict__ sp_out, float* __restrict__ g,
                         float* __restrict__ acc) {
    if (blockIdx.x < 512) {
        // ---- per-pixel CE / probs / focal-BCE partials; store sigmoid(probs)
        int b = blockIdx.x >> 6;                 // 64 blocks per batch (1024 px each)
        int hwbase = (blockIdx.x & 63) * 1024;
        const float* in0 = in + b * 2 * HW;
        const float* in1 = in0 + HW;

        float ce = 0.f, inter = 0.f, sump = 0.f, fse = 0.f, tc = 0.f;
        #pragma unroll
        for (int k = 0; k < 4; k++) {
            int hw  = hwbase + k * 256 + threadIdx.x;
            int idx = b * HW + hw;
            float x0 = in0[hw], x1 = in1[hw];
            int   tg = tgt[idx];
            float t  = (tg == 1) ? 1.0f : 0.0f;

            float m   = fmaxf(x0, x1);
            float lse = m + log1pf(expf(fminf(x0, x1) - m));
            ce += lse - ((tg == 1) ? x1 : x0);
            float p = 1.0f / (1.0f + expf(x0 - x1));
            inter += p * t;
            sump  += p;
            tc    += t;

            float z   = 1.0f / (1.0f + expf(-10.0f * (p - 0.5f)));
            float tb  = 1.0f / (1.0f + expf(-10.0f * (t - 0.5f)));
            float bce = log1pf(expf(z)) - tb * z;
            float ptb = expf(-bce);
            float omp = 1.0f - ptb;
            fse += 0.25f * omp * omp * bce;

            sp_out[idx] = 1.0f / (1.0f + expf(-p));
        }
        float v[5]   = {ce, inter, sump, fse, tc};
        float* dst[5] = {acc + 0, acc + 1, acc + 2, acc + 4, acc + 5 + b};
        blockAtomicAdd<5>(v, dst);
    } else {
        // ---- EDT column pass: per-column nearest-background distance, squared
        int gid = (blockIdx.x - 512) * 256 + threadIdx.x;   // 2048 columns
        int b = gid >> 8, w = gid & 255;
        const int* tb = tgt + b * HW + w;
        float* gb = g + b * HW + w;
        int d = 1 << 20;
        for (int h = 0; h < HH; h++) {
            d = (tb[h * WW] == 1) ? (d + 1) : 0;
            gb[h * WW] = (float)d;
        }
        d = 1 << 20;
        for (int h = HH - 1; h >= 0; h--) {
            d = (tb[h * WW] == 1) ? (d + 1) : 0;
            float dv = fminf(gb[h * WW], (float)d);
            gb[h * WW] = (dv >= 1.0e4f) ? 1.0e12f : dv * dv;
        }
    }
}

// Stage 2 (fused): blocks 0..2047 = EDT row pass (one row each);
//                  blocks 2048..2559 = boundary dice.
__global__ void k_stage2(const float* __restrict__ g, const float* __restrict__ sp,
                         const int* __restrict__ tgt, float* __restrict__ acc) {
    if (blockIdx.x < 2048) {
        // ---- EDT row pass + boundary-weight sum; window +/-WIN, INF-padded
        __shared__ float s_g[WW + 2 * WIN];
        int row = blockIdx.x;                  // b*HH + h
        int b = row >> 8;
        int w = threadIdx.x;
        s_g[w + WIN] = g[row * WW + w];
        if (w < WIN) { s_g[w] = 3.0e12f; s_g[WW + WIN + w] = 3.0e12f; }
        __syncthreads();
        float b0 = 3.0e12f, b1 = 3.0e12f, b2 = 3.0e12f, b3 = 3.0e12f;
        #pragma unroll
        for (int j = 0; j <= 2 * WIN; j += 4) {
            float c0 = (float)((j - WIN) * (j - WIN));
            float c1 = (float)((j + 1 - WIN) * (j + 1 - WIN));
            float c2 = (float)((j + 2 - WIN) * (j + 2 - WIN));
            float c3 = (float)((j + 3 - WIN) * (j + 3 - WIN));
            b0 = fminf(b0, c0 + s_g[w + j]);
            if (j + 1 <= 2 * WIN) b1 = fminf(b1, c1 + s_g[w + j + 1]);
            if (j + 2 <= 2 * WIN) b2 = fminf(b2, c2 + s_g[w + j + 2]);
            if (j + 3 <= 2 * WIN) b3 = fminf(b3, c3 + s_g[w + j + 3]);
        }
        float best = fminf(fminf(b0, b1), fminf(b2, b3));
        float bw = 10.0f * expf(-best * (1.0f / 98.0f));
        float v[1]   = {bw};
        float* dst[1] = {acc + 13 + b};
        blockAtomicAdd<1>(v, dst);
    } else {
        // ---- boundary dice: 7x7 zero-padded box sums, 4 px/thread
        int bid = blockIdx.x - 2048;           // 0..511
        int b = bid >> 6;
        int hwbase = (bid & 63) * 1024;
        const float* spb = sp + b * HW;
        const int*   tb  = tgt + b * HW;
        float vpb = 0.f, vgb = 0.f, vpg = 0.f;
        for (int k = 0; k < 4; k++) {
            int hw = hwbase + k * 256 + threadIdx.x;
            int h = hw >> 8, w = hw & 255;
            float cp = 0.0f; int cg = 0;
            #pragma unroll
            for (int dy = -3; dy <= 3; dy++) {
                int hh = h + dy;
                if (hh < 0 || hh >= HH) continue;
                #pragma unroll
                for (int dx = -3; dx <= 3; dx++) {
                    int ww = w + dx;
                    if (ww < 0 || ww >= WW) continue;
                    cp += spb[hh * WW + ww];
                    cg += (tb[hh * WW + ww] == 1);
                }
            }
            float pb = (cp > 0.0f && cp < 49.0f) ? 1.0f : 0.0f;
            float gb = (cg > 0 && cg < 49) ? 1.0f : 0.0f;
            vpb += pb; vgb += gb; vpg += pb * gb;
        }
        float v[3]   = {vpb, vgb, vpg};
        float* dst[3] = {acc + 21, acc + 22, acc + 23};
        blockAtomicAdd<3>(v, dst);
    }
}

__global__ void k_final(const float* __restrict__ acc, float* __restrict__ out) {
    float sumt = 0.0f;
    for (int b = 0; b < BB; b++) sumt += acc[5 + b];
    float ce = acc[0] / (float)NTOT;
    float inter = acc[1], sump = acc[2];
    float dice = 1.0f - (2.0f * inter + 1e-6f) / (sump + sumt + 1e-6f);
    float pt = expf(-ce);
    float focal = 0.25f * (1.0f - pt) * (1.0f - pt) * ce;
    float fp = sump - inter, fn = sumt - inter;
    float tversky = 1.0f - inter / (inter + 0.7f * fp + 0.3f * fn);
    float ftv = tversky * tversky;
    float focal_ce = acc[4] / (float)NTOT;
    float s = 0.0f;
    for (int b = 0; b < BB; b++) s += 1.0f / (acc[5 + b] + 1e-6f);
    float cwsum = 0.0f;
    for (int b = 0; b < BB; b++) cwsum += (1.0f / (acc[5 + b] + 1e-6f)) / s;
    float bwsum = 0.0f;
    for (int b = 0; b < BB; b++) if (acc[5 + b] > 0.0f) bwsum += acc[13 + b];
    float wfce = focal_ce * cwsum * bwsum / ((float)BB * (float)BB * (float)HW);
    float bndice = 1.0f - (2.0f * acc[23] + 1e-6f) / (acc[21] + acc[22] + 1e-6f);
    out[0] = 2.0f * dice + focal + ce + ftv + wfce + bndice;
}

extern "C" void kernel_launch(void* const* d_in, const int* in_sizes, int n_in,
                              void* d_out, int out_size, void* d_ws, size_t ws_size,
                              hipStream_t stream) {
    const float* in  = (const float*)d_in[0];
    const int*   tgt = (const int*)d_in[1];
    float* out = (float*)d_out;
    float* sp  = (float*)d_ws;          // NTOT floats: sigmoid(probs)
    float* g   = sp + NTOT;             // NTOT floats: EDT intermediate
    float* acc = g + NTOT;              // ACC_N floats

    k_zero<<<1, 64, 0, stream>>>(acc);
    k_stage1<<<520, 256, 0, stream>>>(in, tgt, sp, g, acc);
    k_stage2<<<2560, 256, 0, stream>>>(g, sp, tgt, acc);
    k_final<<<1, 1, 0, stream>>>(acc, out);
}

// Round 4
// 64.654 us; speedup vs baseline: 16.7777x; 1.4218x over previous
//
#include <hip/hip_runtime.h>
#include <math.h>

#define BB 8
#define HH 256
#define WW 256
#define HW (HH*WW)
#define NTOT (BB*HW)

// acc layout (floats):
// 0 ce_sum, 1 inter, 2 sum_probs, 3 (unused), 4 focal_ce_sum,
// 5..12 counts[b], 13..20 bwsum[b], 22 sum_gb
#define ACC_N 24

#define WIN 48   // EDT row-pass window; contributions beyond are < 1e-9

// Block-wide reduction (blockDim == 256 = 4 waves) + one atomic per value.
template<int N>
__device__ __forceinline__ void blockAtomicAdd(float (&v)[N], float* const (&dst)[N]) {
    __shared__ float s[N][4];
    int lane = threadIdx.x & 63, wid = threadIdx.x >> 6;
    #pragma unroll
    for (int j = 0; j < N; j++) {
        float x = v[j];
        #pragma unroll
        for (int o = 32; o > 0; o >>= 1) x += __shfl_down(x, o, 64);
        if (lane == 0) s[j][wid] = x;
    }
    __syncthreads();
    if (threadIdx.x < N) {
        float x = s[threadIdx.x][0] + s[threadIdx.x][1] + s[threadIdx.x][2] + s[threadIdx.x][3];
        atomicAdd(dst[threadIdx.x], x);
    }
}

__global__ void k_zero(float* acc) {
    if (threadIdx.x < ACC_N) acc[threadIdx.x] = 0.0f;
}

// Stage 1 (fused, 776 blocks):
//   [0,512)   per-pixel CE / probs / focal-BCE partials (4 px/thread, float4)
//   [512,520) EDT column pass
//   [520,776) boundary dice gb (separable 7x7 box sum via LDS)
__global__ void k_stage1(const float* __restrict__ in, const int* __restrict__ tgt,
                         float* __restrict__ g, float* __restrict__ acc) {
    if (blockIdx.x < 512) {
        int b = blockIdx.x >> 6;                 // 64 blocks per batch
        int hw0 = (blockIdx.x & 63) * 1024 + threadIdx.x * 4;
        const float* in0 = in + b * 2 * HW;
        const float* in1 = in0 + HW;
        float4 x0v = *(const float4*)(in0 + hw0);
        float4 x1v = *(const float4*)(in1 + hw0);
        int4   tgv = *(const int4*)(tgt + b * HW + hw0);
        float xa[4] = {x0v.x, x0v.y, x0v.z, x0v.w};
        float xb[4] = {x1v.x, x1v.y, x1v.z, x1v.w};
        int   tg[4] = {tgv.x, tgv.y, tgv.z, tgv.w};

        float ce = 0.f, inter = 0.f, sump = 0.f, fse = 0.f, tc = 0.f;
        #pragma unroll
        for (int k = 0; k < 4; k++) {
            float x0 = xa[k], x1 = xb[k];
            bool  t1 = (tg[k] == 1);
            float t  = t1 ? 1.0f : 0.0f;
            // ce = softplus(x_other - x_target)
            float dt = t1 ? (x0 - x1) : (x1 - x0);
            ce += fmaxf(dt, 0.0f) + __logf(1.0f + __expf(-fabsf(dt)));
            float p = 1.0f / (1.0f + __expf(x0 - x1));
            inter += p * t;
            sump  += p;
            tc    += t;
            float z   = 1.0f / (1.0f + __expf(-10.0f * (p - 0.5f)));
            float tb  = t1 ? 0.9933071491f : 0.0066928509f;   // sigmoid(+-5)
            float bce = __logf(1.0f + __expf(z)) - tb * z;
            float ptb = __expf(-bce);
            float omp = 1.0f - ptb;
            fse += 0.25f * omp * omp * bce;
        }
        float v[5]   = {ce, inter, sump, fse, tc};
        float* dst[5] = {acc + 0, acc + 1, acc + 2, acc + 4, acc + 5 + b};
        blockAtomicAdd<5>(v, dst);
    } else if (blockIdx.x < 520) {
        // ---- EDT column pass: per-column nearest-background distance, squared
        int gid = (blockIdx.x - 512) * 256 + threadIdx.x;   // 2048 columns
        int b = gid >> 8, w = gid & 255;
        const int* tb = tgt + b * HW + w;
        float* gb = g + b * HW + w;
        int d = 1 << 20;
        for (int h = 0; h < HH; h++) {
            d = (tb[h * WW] == 1) ? (d + 1) : 0;
            gb[h * WW] = (float)d;
        }
        d = 1 << 20;
        for (int h = HH - 1; h >= 0; h--) {
            d = (tb[h * WW] == 1) ? (d + 1) : 0;
            float dv = fminf(gb[h * WW], (float)d);
            gb[h * WW] = (dv >= 1.0e4f) ? 1.0e12f : dv * dv;
        }
    } else {
        // ---- boundary dice: gb only (pb==1 identically: sigmoid(probs) box
        //      sums are always in (8, 35.9) strictly inside (0,49)).
        __shared__ int t_s[14][WW];
        __shared__ int vs_s[8][WW + 6];
        int bid = blockIdx.x - 520;            // 0..255
        int b = bid >> 5;                      // 32 strips of 8 rows per batch
        int y0 = (bid & 31) * 8;
        int x = threadIdx.x;
        #pragma unroll
        for (int r = 0; r < 14; r++) {
            int y = y0 - 3 + r;
            t_s[r][x] = (y >= 0 && y < HH) ? (tgt[b * HW + y * WW + x] == 1) : 0;
        }
        __syncthreads();
        int v0 = 0;
        #pragma unroll
        for (int r = 0; r < 7; r++) v0 += t_s[r][x];
        int vr[8];
        vr[0] = v0;
        #pragma unroll
        for (int r = 1; r < 8; r++) vr[r] = vr[r - 1] - t_s[r - 1][x] + t_s[r + 6][x];
        #pragma unroll
        for (int r = 0; r < 8; r++) vs_s[r][x + 3] = vr[r];
        if (x < 3) {
            #pragma unroll
            for (int r = 0; r < 8; r++) { vs_s[r][x] = 0; vs_s[r][WW + 3 + x] = 0; }
        }
        __syncthreads();
        float gbsum = 0.0f;
        #pragma unroll
        for (int r = 0; r < 8; r++) {
            int c = vs_s[r][x] + vs_s[r][x + 1] + vs_s[r][x + 2] + vs_s[r][x + 3]
                  + vs_s[r][x + 4] + vs_s[r][x + 5] + vs_s[r][x + 6];
            gbsum += (c > 0 && c < 49) ? 1.0f : 0.0f;
        }
        float v[1]   = {gbsum};
        float* dst[1] = {acc + 22};
        blockAtomicAdd<1>(v, dst);
    }
}

// Stage 2: EDT row pass (one row per block) + boundary-weight sum.
__global__ void k_stage2(const float* __restrict__ g, float* __restrict__ acc) {
    __shared__ float s_g[WW + 2 * WIN];
    int row = blockIdx.x;                  // b*HH + h
    int b = row >> 8;
    int w = threadIdx.x;
    s_g[w + WIN] = g[row * WW + w];
    if (w < WIN) { s_g[w] = 3.0e12f; s_g[WW + WIN + w] = 3.0e12f; }
    __syncthreads();
    float b0 = 3.0e12f, b1 = 3.0e12f, b2 = 3.0e12f, b3 = 3.0e12f;
    #pragma unroll
    for (int j = 0; j <= 2 * WIN; j += 4) {
        float c0 = (float)((j - WIN) * (j - WIN));
        float c1 = (float)((j + 1 - WIN) * (j + 1 - WIN));
        float c2 = (float)((j + 2 - WIN) * (j + 2 - WIN));
        float c3 = (float)((j + 3 - WIN) * (j + 3 - WIN));
        b0 = fminf(b0, c0 + s_g[w + j]);
        if (j + 1 <= 2 * WIN) b1 = fminf(b1, c1 + s_g[w + j + 1]);
        if (j + 2 <= 2 * WIN) b2 = fminf(b2, c2 + s_g[w + j + 2]);
        if (j + 3 <= 2 * WIN) b3 = fminf(b3, c3 + s_g[w + j + 3]);
    }
    float best = fminf(fminf(b0, b1), fminf(b2, b3));
    float bw = 10.0f * __expf(-best * (1.0f / 98.0f));
    float v[1]   = {bw};
    float* dst[1] = {acc + 13 + b};
    blockAtomicAdd<1>(v, dst);
}

__global__ void k_final(const float* __restrict__ acc, float* __restrict__ out) {
    float sumt = 0.0f;
    for (int b = 0; b < BB; b++) sumt += acc[5 + b];
    float ce = acc[0] / (float)NTOT;
    float inter = acc[1], sump = acc[2];
    float dice = 1.0f - (2.0f * inter + 1e-6f) / (sump + sumt + 1e-6f);
    float pt = expf(-ce);
    float focal = 0.25f * (1.0f - pt) * (1.0f - pt) * ce;
    float fp = sump - inter, fn = sumt - inter;
    float tversky = 1.0f - inter / (inter + 0.7f * fp + 0.3f * fn);
    float ftv = tversky * tversky;
    float focal_ce = acc[4] / (float)NTOT;
    float s = 0.0f;
    for (int b = 0; b < BB; b++) s += 1.0f / (acc[5 + b] + 1e-6f);
    float cwsum = 0.0f;
    for (int b = 0; b < BB; b++) cwsum += (1.0f / (acc[5 + b] + 1e-6f)) / s;
    float bwsum = 0.0f;
    for (int b = 0; b < BB; b++) if (acc[5 + b] > 0.0f) bwsum += acc[13 + b];
    float wfce = focal_ce * cwsum * bwsum / ((float)BB * (float)BB * (float)HW);
    // pb == 1 everywhere: sum_pb = NTOT, sum(pb*gb) = sum_gb
    float sgb = acc[22];
    float bndice = 1.0f - (2.0f * sgb + 1e-6f) / ((float)NTOT + sgb + 1e-6f);
    out[0] = 2.0f * dice + focal + ce + ftv + wfce + bndice;
}

extern "C" void kernel_launch(void* const* d_in, const int* in_sizes, int n_in,
                              void* d_out, int out_size, void* d_ws, size_t ws_size,
                              hipStream_t stream) {
    const float* in  = (const float*)d_in[0];
    const int*   tgt = (const int*)d_in[1];
    float* out = (float*)d_out;
    float* g   = (float*)d_ws;          // NTOT floats: EDT intermediate
    float* acc = g + NTOT;              // ACC_N floats

    k_zero<<<1, 64, 0, stream>>>(acc);
    k_stage1<<<776, 256, 0, stream>>>(in, tgt, g, acc);
    k_stage2<<<2048, 256, 0, stream>>>(g, acc);
    k_final<<<1, 1, 0, stream>>>(acc, out);
}

// Round 5
// 21.202 us; speedup vs baseline: 51.1633x; 3.0495x over previous
//
#include <hip/hip_runtime.h>
#include <math.h>

#define BB 8
#define HH 256
#define WW 256
#define HW (HH*WW)
#define NTOT (BB*HW)

// partials layout in d_ws (floats) — every slot written every call (poison-safe):
// [0,512) ce | [512,1024) inter | [1024,1536) sump | [1536,2048) fse
// [2048,2560) tc per main-block (b=bid>>6)
// [2560,2816) bw per edt-block (b=e>>5)
// [2816,3072) gb per boundary-block
#define P_CE    0
#define P_INTER 512
#define P_SUMP  1024
#define P_FSE   1536
#define P_TC    2048
#define P_BW    2560
#define P_GB    2816

// Block-wide sum of N scalars (blockDim=256); result valid in all threads.
template<int N>
__device__ __forceinline__ void blockSum(float (&v)[N]) {
    __shared__ float s[N][4];
    int lane = threadIdx.x & 63, wid = threadIdx.x >> 6;
    #pragma unroll
    for (int j = 0; j < N; j++) {
        float x = v[j];
        #pragma unroll
        for (int o = 32; o > 0; o >>= 1) x += __shfl_down(x, o, 64);
        if (lane == 0) s[j][wid] = x;
    }
    __syncthreads();
    #pragma unroll
    for (int j = 0; j < N; j++) v[j] = s[j][0] + s[j][1] + s[j][2] + s[j][3];
}

// Fused stage: [0,512) per-pixel pass; [512,768) EDT (col+row, windowed, in-LDS);
//              [768,1024) boundary dice gb.
__global__ void k_fused(const float* __restrict__ in, const int* __restrict__ tgt,
                        float* __restrict__ P) {
    int bid = blockIdx.x;
    if (bid < 512) {
        // ---- per-pixel CE / probs / focal-BCE partials (4 px/thread, float4)
        int b = bid >> 6;
        int hw0 = (bid & 63) * 1024 + threadIdx.x * 4;
        const float* in0 = in + b * 2 * HW;
        const float* in1 = in0 + HW;
        float4 x0v = *(const float4*)(in0 + hw0);
        float4 x1v = *(const float4*)(in1 + hw0);
        int4   tgv = *(const int4*)(tgt + b * HW + hw0);
        float xa[4] = {x0v.x, x0v.y, x0v.z, x0v.w};
        float xb[4] = {x1v.x, x1v.y, x1v.z, x1v.w};
        int   tg[4] = {tgv.x, tgv.y, tgv.z, tgv.w};

        float ce = 0.f, inter = 0.f, sump = 0.f, fse = 0.f, tc = 0.f;
        #pragma unroll
        for (int k = 0; k < 4; k++) {
            float x0 = xa[k], x1 = xb[k];
            bool  t1 = (tg[k] == 1);
            float t  = t1 ? 1.0f : 0.0f;
            float dt = t1 ? (x0 - x1) : (x1 - x0);
            ce += fmaxf(dt, 0.0f) + __logf(1.0f + __expf(-fabsf(dt)));
            float p = 1.0f / (1.0f + __expf(x0 - x1));
            inter += p * t;
            sump  += p;
            tc    += t;
            float z   = 1.0f / (1.0f + __expf(-10.0f * (p - 0.5f)));
            float tb  = t1 ? 0.9933071491f : 0.0066928509f;   // sigmoid(+-5)
            float bce = __logf(1.0f + __expf(z)) - tb * z;
            float ptb = __expf(-bce);
            float omp = 1.0f - ptb;
            fse += 0.25f * omp * omp * bce;
        }
        float v[5] = {ce, inter, sump, fse, tc};
        blockSum<5>(v);
        if (threadIdx.x == 0) {
            P[P_CE + bid] = v[0]; P[P_INTER + bid] = v[1];
            P[P_SUMP + bid] = v[2]; P[P_FSE + bid] = v[3];
            P[P_TC + bid] = v[4];
        }
    } else if (bid < 768) {
        // ---- EDT, fully in-block: 8-row tile, +-48 halo via 104-bit column mask.
        // Distances > 48 are clamped to 1e12 (bw contribution < 1e-9: provably
        // negligible); out-of-image rows are fg (no reset), matching reference.
        __shared__ __align__(16) float s_g[8][352];   // [row][48 pad | 256 | 48 pad]
        int e = bid - 512;            // 0..255
        int b = e >> 5;
        int y0 = (e & 31) * 8;
        int w = threadIdx.x;
        const int* tb = tgt + b * HW + w;
        unsigned int m0 = 0, m1 = 0, m2 = 0, m3 = 0;  // bit k = row y0-48+k is fg
        #pragma unroll
        for (int k = 0; k < 104; k++) {
            int y = y0 - 48 + k;
            int yc = y < 0 ? 0 : (y > 255 ? 255 : y);
            unsigned int t = (unsigned int)(tb[yc * WW] == 1);
            if (y < 0 || y > 255) t = 1u;
            if (k < 32)      m0 |= t << k;
            else if (k < 64) m1 |= t << (k - 32);
            else if (k < 96) m2 |= t << (k - 64);
            else             m3 |= t << (k - 96);
        }
        unsigned long long ulo = (unsigned long long)m0 | ((unsigned long long)m1 << 32);
        unsigned long long uhi = (unsigned long long)m2 | ((unsigned long long)m3 << 32);
        unsigned long long nlo = ~ulo, nhi = ~uhi;    // 1 = background
        #pragma unroll
        for (int i = 0; i < 8; i++) {
            int ki = 48 + i;
            unsigned long long zlo = nlo & ((2ull << ki) - 1ull);
            int up = zlo ? (ki - (63 - __clzll(zlo))) : 64;
            unsigned long long f = (nlo >> ki) | (nhi << (64 - ki));
            int dn = f ? (__ffsll((long long)f) - 1) : 64;
            int dist = up < dn ? up : dn;
            s_g[i][w + 48] = (dist > 48) ? 1.0e12f : (float)(dist * dist);
        }
        if (w < 48) {
            #pragma unroll
            for (int i = 0; i < 8; i++) { s_g[i][w] = 1.0e12f; s_g[i][304 + w] = 1.0e12f; }
        }
        __syncthreads();
        // row min-plus: thread = (col-group of 4, row slot); float4 LDS reads.
        int cg = threadIdx.x & 63;    // w0 = 4*cg
        int rr = threadIdx.x >> 6;    // rows rr, rr+4
        float bwsum = 0.0f;
        #pragma unroll
        for (int rj = 0; rj < 2; rj++) {
            int r = rr + rj * 4;
            float b0 = 3e12f, b1 = 3e12f, b2 = 3e12f, b3 = 3e12f;
            #pragma unroll
            for (int k = 0; k < 25; k++) {
                float4 gq = *(const float4*)&s_g[r][4 * cg + 4 * k];
                #define T4(gg, rel) \
                    b0 = fminf(b0, (gg) + (float)(((rel)-48)*((rel)-48))); \
                    b1 = fminf(b1, (gg) + (float)(((rel)-49)*((rel)-49))); \
                    b2 = fminf(b2, (gg) + (float)(((rel)-50)*((rel)-50))); \
                    b3 = fminf(b3, (gg) + (float)(((rel)-51)*((rel)-51)));
                T4(gq.x, 4*k+0) T4(gq.y, 4*k+1) T4(gq.z, 4*k+2) T4(gq.w, 4*k+3)
                #undef T4
            }
            bwsum += 10.0f * (__expf(-b0 * (1.0f/98.0f)) + __expf(-b1 * (1.0f/98.0f))
                            + __expf(-b2 * (1.0f/98.0f)) + __expf(-b3 * (1.0f/98.0f)));
        }
        float v[1] = {bwsum};
        blockSum<1>(v);
        if (threadIdx.x == 0) P[P_BW + e] = v[0];
    } else {
        // ---- boundary dice gb (pb==1 identically; separable 7x7 box sum)
        __shared__ int t_s[14][WW];
        __shared__ int vs_s[8][WW + 6];
        int bid2 = bid - 768;          // 0..255
        int b = bid2 >> 5;
        int y0 = (bid2 & 31) * 8;
        int x = threadIdx.x;
        #pragma unroll
        for (int r = 0; r < 14; r++) {
            int y = y0 - 3 + r;
            t_s[r][x] = (y >= 0 && y < HH) ? (tgt[b * HW + y * WW + x] == 1) : 0;
        }
        __syncthreads();
        int v0 = 0;
        #pragma unroll
        for (int r = 0; r < 7; r++) v0 += t_s[r][x];
        int vr[8];
        vr[0] = v0;
        #pragma unroll
        for (int r = 1; r < 8; r++) vr[r] = vr[r - 1] - t_s[r - 1][x] + t_s[r + 6][x];
        #pragma unroll
        for (int r = 0; r < 8; r++) vs_s[r][x + 3] = vr[r];
        if (x < 3) {
            #pragma unroll
            for (int r = 0; r < 8; r++) { vs_s[r][x] = 0; vs_s[r][WW + 3 + x] = 0; }
        }
        __syncthreads();
        float gbsum = 0.0f;
        #pragma unroll
        for (int r = 0; r < 8; r++) {
            int c = vs_s[r][x] + vs_s[r][x + 1] + vs_s[r][x + 2] + vs_s[r][x + 3]
                  + vs_s[r][x + 4] + vs_s[r][x + 5] + vs_s[r][x + 6];
            gbsum += (c > 0 && c < 49) ? 1.0f : 0.0f;
        }
        float v[1] = {gbsum};
        blockSum<1>(v);
        if (threadIdx.x == 0) P[P_GB + bid2] = v[0];
    }
}

__global__ void k_final(const float* __restrict__ P, float* __restrict__ out) {
    __shared__ float sred[5][4];
    __shared__ float s_tc[8], s_bw[8];
    int t = threadIdx.x, lane = t & 63, wid = t >> 6;
    float vals[5];
    vals[0] = P[P_CE + t]    + P[P_CE + 256 + t];
    vals[1] = P[P_INTER + t] + P[P_INTER + 256 + t];
    vals[2] = P[P_SUMP + t]  + P[P_SUMP + 256 + t];
    vals[3] = P[P_FSE + t]   + P[P_FSE + 256 + t];
    vals[4] = P[P_GB + t];
    #pragma unroll
    for (int j = 0; j < 5; j++) {
        float x = vals[j];
        #pragma unroll
        for (int o = 32; o > 0; o >>= 1) x += __shfl_down(x, o, 64);
        if (lane == 0) sred[j][wid] = x;
    }
    int b = t >> 5, l32 = t & 31;
    float tc = P[P_TC + b * 64 + l32] + P[P_TC + b * 64 + 32 + l32];
    float bw = P[P_BW + b * 32 + l32];
    #pragma unroll
    for (int o = 16; o > 0; o >>= 1) {
        tc += __shfl_down(tc, o, 32);
        bw += __shfl_down(bw, o, 32);
    }
    if (l32 == 0) { s_tc[b] = tc; s_bw[b] = bw; }
    __syncthreads();
    if (t == 0) {
        float ce_sum = sred[0][0] + sred[0][1] + sred[0][2] + sred[0][3];
        float inter  = sred[1][0] + sred[1][1] + sred[1][2] + sred[1][3];
        float sump   = sred[2][0] + sred[2][1] + sred[2][2] + sred[2][3];
        float fse    = sred[3][0] + sred[3][1] + sred[3][2] + sred[3][3];
        float sgb    = sred[4][0] + sred[4][1] + sred[4][2] + sred[4][3];
        float sumt = 0.0f;
        for (int i = 0; i < BB; i++) sumt += s_tc[i];
        float ce = ce_sum / (float)NTOT;
        float dice = 1.0f - (2.0f * inter + 1e-6f) / (sump + sumt + 1e-6f);
        float pt = expf(-ce);
        float focal = 0.25f * (1.0f - pt) * (1.0f - pt) * ce;
        float fp = sump - inter, fn = sumt - inter;
        float tversky = 1.0f - inter / (inter + 0.7f * fp + 0.3f * fn);
        float ftv = tversky * tversky;
        float focal_ce = fse / (float)NTOT;
        float s = 0.0f;
        for (int i = 0; i < BB; i++) s += 1.0f / (s_tc[i] + 1e-6f);
        float cwsum = 0.0f;
        for (int i = 0; i < BB; i++) cwsum += (1.0f / (s_tc[i] + 1e-6f)) / s;
        float bwsum = 0.0f;
        for (int i = 0; i < BB; i++) if (s_tc[i] > 0.0f) bwsum += s_bw[i];
        float wfce = focal_ce * cwsum * bwsum / ((float)BB * (float)BB * (float)HW);
        // pb == 1 everywhere: sum_pb = NTOT, sum(pb*gb) = sum_gb
        float bndice = 1.0f - (2.0f * sgb + 1e-6f) / ((float)NTOT + sgb + 1e-6f);
        out[0] = 2.0f * dice + focal + ce + ftv + wfce + bndice;
    }
}

extern "C" void kernel_launch(void* const* d_in, const int* in_sizes, int n_in,
                              void* d_out, int out_size, void* d_ws, size_t ws_size,
                              hipStream_t stream) {
    const float* in  = (const float*)d_in[0];
    const int*   tgt = (const int*)d_in[1];
    float* out = (float*)d_out;
    float* P   = (float*)d_ws;          // 3072 partial floats

    k_fused<<<1024, 256, 0, stream>>>(in, tgt, P);
    k_final<<<1, 256, 0, stream>>>(P, out);
}